// Round 13
// baseline (269.122 us; speedup 1.0000x reference)
//
#include <hip/hip_runtime.h>
#include <math.h>

#define SUB 20       // sub_no
#define NC 19        // sub_no - 1
#define TSYN 200
#define THIST 50
#define BNUM 3
#define LSEG 16      // live segment length per block (NB=625 at T=10000)
#define WARMS 32     // spike warm-up steps: decay<=0.4 by construction -> 0.4^32~2e-13
#define WARMY 36     // Y warm-up: empirical rho<=0.85 (R7/R8 A/B) -> 0.85^36~3e-3 << 2e-2
#define SCH 64       // spk staging chunk (>= LSEG+WARMS = 48)
#define SCHP (SCH+4)
#define YLEN (LSEG+WARMY)   // 52: per-block step window in k_yA
#define ACHP (YLEN+4)       // 56: A-buffer row stride
#define WLEN (THIST+YLEN+5) // 107: odd row stride (11 mod 32) -> conflict-free banks
#define TKST 51             // padded tap-row stride (19 mod 32, odd) -> conflict-free

// ---------------------------------------------------------------------------
// k_prep: assignment indices from one-hot C_syn, plus the three alpha-basis
// kernels (syn with delta shift, hist, prop).
// ---------------------------------------------------------------------------
__global__ void k_prep(const float* __restrict__ C_syn_e, const float* __restrict__ C_syn_i,
                       const float* __restrict__ W_ns_syn, const float* __restrict__ Delta_ns_syn,
                       const float* __restrict__ W_ns_hist, const float* __restrict__ W_ns_prop,
                       int* __restrict__ ae, int* __restrict__ ai,
                       float* __restrict__ ke, float* __restrict__ ki,
                       float* __restrict__ histk, float* __restrict__ propk,
                       int E, int I)
{
    int idx = blockIdx.x * blockDim.x + threadIdx.x;
    if (idx < E) {
        int a = 0;
        for (int s = 0; s < SUB; ++s) if (C_syn_e[(size_t)s * E + idx] != 0.f) a = s;
        ae[idx] = a;
        return;
    }
    idx -= E;
    if (idx < I) {
        int a = 0;
        for (int s = 0; s < SUB; ++s) if (C_syn_i[(size_t)s * I + idx] != 0.f) a = s;
        ai[idx] = a;
        return;
    }
    idx -= I;
    if (idx < SUB * 2 * TSYN) {
        int j   = idx % TSYN;
        int rem = idx / TSYN;
        int c2  = rem & 1;
        int s   = rem >> 1;
        float delta = expf(Delta_ns_syn[s * 2 + c2]);
        float ts = fmaxf((float)j - delta, 0.f);
        float acc = 0.f;
        for (int b = 0; b < BNUM; ++b) {
            float tau = expf((float)b);
            float tt = ts / tau;
            acc += W_ns_syn[s * 6 + b * 2 + c2] * tt * expf(-tt);
        }
        if (c2 == 0) ke[s * TSYN + j] = acc; else ki[s * TSYN + j] = acc;
        return;
    }
    idx -= SUB * 2 * TSYN;
    if (idx < NC * THIST) {
        int j = idx % THIST, c = idx / THIST;
        float acc = 0.f;
        for (int b = 0; b < BNUM; ++b) {
            float tau = expf((float)b);
            float tt = (float)j / tau;
            acc += W_ns_hist[c * 3 + b] * tt * expf(-tt);
        }
        histk[c * THIST + j] = acc;
        return;
    }
    idx -= NC * THIST;
    if (idx < SUB * THIST) {
        int j = idx % THIST, s = idx / THIST;
        float acc = 0.f;
        for (int b = 0; b < BNUM; ++b) {
            float tau = expf((float)b);
            float tt = (float)j / tau;
            acc += W_ns_prop[s * 3 + b] * tt * expf(-tt);
        }
        propk[s * THIST + j] = acc;
    }
}

// ---------------------------------------------------------------------------
// k_insum: segment-sum, 4 TIMESTEPS PER BLOCK (2500 blocks at T=10000):
// float4 spike loads, LDS rows per timestep, coalesced float4 output writes
// into the transposed [s][t] layouts + fused somatic drive syn_sT[c][t].
// Spike values are sums of 1.0s -> exact in fp32 under any atomic order.
// ---------------------------------------------------------------------------
__global__ void k_insum(const float* __restrict__ Se, const float* __restrict__ Si,
                        const int* __restrict__ ae, const int* __restrict__ ai,
                        const float* __restrict__ W_s_syn,
                        float* __restrict__ in_eT, float* __restrict__ in_iT,
                        float* __restrict__ syn_sT,
                        int T, int E, int I)
{
    int tbase = 4 * blockIdx.x;
    int nt = min(4, T - tbase);
    __shared__ float le[4 * 21], li[4 * 21];   // stride 21: bank-spread
    for (int r = threadIdx.x; r < 4 * 21; r += blockDim.x) { le[r] = 0.f; li[r] = 0.f; }
    __syncthreads();
    for (int tt = 0; tt < nt; ++tt) {
        const float* Ser = Se + (size_t)(tbase + tt) * E;
        const float* Sir = Si + (size_t)(tbase + tt) * I;
        int E4 = E >> 2, I4 = I >> 2;
        float* lerow = &le[tt * 21];
        float* lirow = &li[tt * 21];
        for (int e4 = threadIdx.x; e4 < E4; e4 += blockDim.x) {
            float4 v = *(const float4*)(Ser + 4 * e4);
            if (v.x != 0.f) atomicAdd(&lerow[ae[4 * e4 + 0]], v.x);
            if (v.y != 0.f) atomicAdd(&lerow[ae[4 * e4 + 1]], v.y);
            if (v.z != 0.f) atomicAdd(&lerow[ae[4 * e4 + 2]], v.z);
            if (v.w != 0.f) atomicAdd(&lerow[ae[4 * e4 + 3]], v.w);
        }
        for (int e = 4 * E4 + threadIdx.x; e < E; e += blockDim.x) {
            float v = Ser[e];
            if (v != 0.f) atomicAdd(&lerow[ae[e]], v);
        }
        for (int i4 = threadIdx.x; i4 < I4; i4 += blockDim.x) {
            float4 v = *(const float4*)(Sir + 4 * i4);
            if (v.x != 0.f) atomicAdd(&lirow[ai[4 * i4 + 0]], v.x);
            if (v.y != 0.f) atomicAdd(&lirow[ai[4 * i4 + 1]], v.y);
            if (v.z != 0.f) atomicAdd(&lirow[ai[4 * i4 + 2]], v.z);
            if (v.w != 0.f) atomicAdd(&lirow[ai[4 * i4 + 3]], v.w);
        }
        for (int i = 4 * I4 + threadIdx.x; i < I; i += blockDim.x) {
            float v = Sir[i];
            if (v != 0.f) atomicAdd(&lirow[ai[i]], v);
        }
    }
    __syncthreads();
    int s = threadIdx.x;
    if (s < SUB) {
        float4 ve = make_float4(le[0 * 21 + s], le[1 * 21 + s], le[2 * 21 + s], le[3 * 21 + s]);
        float4 vi = make_float4(li[0 * 21 + s], li[1 * 21 + s], li[2 * 21 + s], li[3 * 21 + s]);
        if (nt == 4) {
            *(float4*)(in_eT + (size_t)s * T + tbase) = ve;
            *(float4*)(in_iT + (size_t)s * T + tbase) = vi;
            if (s >= 1) {
                float w0 = W_s_syn[s * 2 + 0], w1 = W_s_syn[s * 2 + 1];
                float4 vs = make_float4(ve.x * w0 + vi.x * w1, ve.y * w0 + vi.y * w1,
                                        ve.z * w0 + vi.z * w1, ve.w * w0 + vi.w * w1);
                *(float4*)(syn_sT + (size_t)(s - 1) * T + tbase) = vs;
            }
        } else {
            for (int tt = 0; tt < nt; ++tt) {
                float e = le[tt * 21 + s], i = li[tt * 21 + s];
                in_eT[(size_t)s * T + tbase + tt] = e;
                in_iT[(size_t)s * T + tbase + tt] = i;
                if (s >= 1)
                    syn_sT[(size_t)(s - 1) * T + tbase + tt] =
                        e * W_s_syn[s * 2 + 0] + i * W_s_syn[s * 2 + 1];
            }
        }
    }
}

// ---------------------------------------------------------------------------
// k_spkconv: FUSED dispatch. Blocks [0,NB): time-parallel spike recurrence
// (16-step live + 32-step warm-up; per-step math identical to R5-R12;
// epilogue computes Z/X outputs, transposed Z_T and fused PZ_T). Blocks
// [NB,...): 200-tap causal conv hidden under the latency-bound spike blocks.
// ---------------------------------------------------------------------------
__global__ __launch_bounds__(64) void k_spkconv(
                      const float* __restrict__ syn_sT,
                      const float* __restrict__ Theta_s, const float* __restrict__ spike_decay,
                      const float* __restrict__ C_den, const float* __restrict__ W_s_prop,
                      float* __restrict__ Zout, float* __restrict__ Xout,
                      float* __restrict__ Z_T, float* __restrict__ PZ_T,
                      const float* __restrict__ in_eT, const float* __restrict__ in_iT,
                      const float* __restrict__ ke, const float* __restrict__ ki,
                      float* __restrict__ syn_nsT,
                      int T, int NB)
{
    __shared__ float S[NC * SCHP];      // staged syn input ([c][tl], float4 rows)
    __shared__ float SX[SCH * SUB];     // buffered x ([tl][c], stride 20)
    __shared__ unsigned ZM[SCH];        // buffered z ballot masks
    __shared__ float PZb[LSEG * SUB];   // fused-pz scratch ([tl][s])
    int lane = threadIdx.x;

    if (blockIdx.x >= NB) {
        // ---- conv part: 4 outputs/thread, sliding-window registers ----
        int T4 = T >> 2;
        int idx = (blockIdx.x - NB) * 64 + lane;
        if (idx >= SUB * T4) return;
        int s = idx / T4, t4 = idx - s * T4;
        int t = 4 * t4;
        const float* be = in_eT + (size_t)s * T;
        const float* bi = in_iT + (size_t)s * T;
        const float* kes = ke + s * TSYN;
        const float* kis = ki + s * TSYN;
        float ea = be[t + 3], eb = be[t + 2], ec = be[t + 1], ed = be[t];
        float ia = bi[t + 3], ib = bi[t + 2], ic = bi[t + 1], id = bi[t];
        float a0 = 0.f, a1 = 0.f, a2 = 0.f, a3 = 0.f;
        int jend = min(TSYN - 1, t + 3);
        for (int j = 0; j <= jend; ++j) {
            float kej = kes[j], kij = kis[j];
            a3 = fmaf(ea, kej, a3); a3 = fmaf(ia, kij, a3);
            a2 = fmaf(eb, kej, a2); a2 = fmaf(ib, kij, a2);
            a1 = fmaf(ec, kej, a1); a1 = fmaf(ic, kij, a1);
            a0 = fmaf(ed, kej, a0); a0 = fmaf(id, kij, a0);
            ea = eb; eb = ec; ec = ed;
            ia = ib; ib = ic; ic = id;
            int off = t - 1 - j;
            ed = (off >= 0) ? be[off] : 0.f;
            id = (off >= 0) ? bi[off] : 0.f;
        }
        *(float4*)(syn_nsT + (size_t)s * T + t) = make_float4(a0, a1, a2, a3);
        return;
    }

    // ---- spike part ----
    int c = lane;
    bool act = c < NC;
    int t0 = blockIdx.x * LSEG;
    if (t0 >= T) return;
    int t1 = min(t0 + LSEG, T);
    int tw = max(0, t0 - WARMS);

    float M[NC];
    #pragma unroll
    for (int j = 0; j < NC; ++j)
        M[j] = act ? C_den[(c + 1) * SUB + (j + 1)] * W_s_prop[j] : 0.f;
    float Cp[NC];                        // row for fused PZ: C_den[lane][c+1]
    #pragma unroll
    for (int j = 0; j < NC; ++j)
        Cp[j] = (lane < SUB) ? C_den[lane * SUB + (j + 1)] : 0.f;
    float theta = act ? Theta_s[c] : 0.f;
    float decay = act ? spike_decay[c] : 0.f;

    float x = 0.f;
    unsigned zlo = 0u;
    {
        int tc = tw;
        int len = t1 - tw;               // <= 48, multiple of 4
        __syncthreads();
        for (int r = lane; r < (NC * SCH) / 4; r += 64) {
            int e = r * 4;
            int cc = e >> 6;           // e / SCH
            int tl = e & (SCH - 1);    // e % SCH
            if (tl < len) {
                float4 v = *(const float4*)(syn_sT + (size_t)cc * T + tc + tl);
                *(float4*)(&S[cc * SCHP + tl]) = v;
            }
        }
        __syncthreads();
        float4 cur = act ? *(float4*)(&S[c * SCHP]) : make_float4(0.f, 0.f, 0.f, 0.f);
        for (int g = 0; g < len; g += 4) {
            float4 nxt = (act && g + 4 < len) ? *(float4*)(&S[c * SCHP + g + 4]) : cur;
            #pragma unroll
            for (int q = 0; q < 4; ++q) {
                float syn = (q == 0) ? cur.x : (q == 1) ? cur.y : (q == 2) ? cur.z : cur.w;
                float P = 0.f;
                #pragma unroll
                for (int j = 0; j < NC; ++j) {
                    float b = (float)((zlo >> j) & 1u);
                    P = fmaf(b, M[j], P);               // exact: b in {0,1}
                }
                float xin = fmaf(x, decay, syn);
                xin += P;
                xin += theta;
                bool zb = xin >= 0.f;
                zlo = (unsigned)__ballot(zb);
                x = zb ? 0.f : xin;
                int tl = g + q;
                if (act) SX[tl * SUB + c] = x;
                if (lane == NC) ZM[tl] = zlo;
            }
            cur = nxt;
        }
        __syncthreads();
        int tls = t0 - tw;                  // live range start within chunk
        int nl  = len - tls;                // live steps (== t1 - t0)
        // fused k_pz: PZ[s][u] from ballot masks (parallel across lanes)
        if (lane < SUB) {
            for (int tl = 0; tl < nl; ++tl) {
                unsigned m = ZM[tls + tl];
                float acc = 0.f;
                #pragma unroll
                for (int j = 0; j < NC; ++j)
                    acc = fmaf((float)((m >> j) & 1u), Cp[j], acc);
                PZb[tl * SUB + lane] = acc;
            }
        }
        __syncthreads();
        for (int r = lane; r < nl * NC; r += 64) {
            int tl = r / NC;
            int cc = r - tl * NC;
            size_t o = (size_t)(t0 + tl) * NC + cc;
            Zout[o] = (float)((ZM[tls + tl] >> cc) & 1u);
            Xout[o] = SX[(tls + tl) * SUB + cc];
        }
        for (int r = lane; r < nl * NC; r += 64) {
            int cc = r / nl;
            int tl = r - cc * nl;
            Z_T[(size_t)cc * T + (t0 + tl)] = (float)((ZM[tls + tl] >> cc) & 1u);
        }
        for (int r = lane; r < nl * SUB; r += 64) {
            int cc = r / nl;
            int tl = r - cc * nl;
            PZ_T[(size_t)cc * T + (t0 + tl)] = PZb[tl * SUB + cc];
        }
    }
}

// ---------------------------------------------------------------------------
// k_yA: FUSED A-computation + Y recurrence, TIME-PARALLEL (625 blocks x
// 16-step live + 36-step warm-up). Phase 1: stage PZ_T/Z_T history window
// (zero-padded below t=0 -> branchless tap loops; odd row strides 107/51,
// lane-adjacent rows) + compute A[s][tl] into S. Phase 2: serial Y loop,
// per-step math identical to R5-R12.
// ---------------------------------------------------------------------------
__global__ __launch_bounds__(64) void k_yA(
                    const float* __restrict__ syn_nsT,
                    const float* __restrict__ PZ_T, const float* __restrict__ Z_T,
                    const float* __restrict__ histk, const float* __restrict__ propk,
                    const float* __restrict__ Theta_ns,
                    const float* __restrict__ C_den, const float* __restrict__ W_ns_sub,
                    const float* __restrict__ V_o,
                    float* __restrict__ Vout, float* __restrict__ Yout, int T)
{
    __shared__ float S[SUB * ACHP];     // A ([s][tl])
    __shared__ float PZw[SUB * WLEN];   // PZ history window, zero-padded, stride 107
    __shared__ float Zw[NC * WLEN];     // Z history window, zero-padded, stride 107
    __shared__ float PKw[SUB * TKST];   // prop taps, stride 51
    __shared__ float HKw[NC * TKST];    // hist taps, stride 51
    __shared__ float SY[YLEN * SUB];    // buffered y ([tl][s])
    __shared__ __align__(16) float ybc[64];
    int lane = threadIdx.x;
    int s = lane;
    bool act = s < SUB;
    int t0 = blockIdx.x * LSEG;
    if (t0 >= T) return;
    int t1 = min(t0 + LSEG, T);
    int tw = max(0, t0 - WARMY);
    int len = t1 - tw;                   // <= 52, multiple of 4
    int wb = tw - THIST;                 // window base (may be negative)

    float Crow[SUB];
    #pragma unroll
    for (int j = 0; j < SUB; ++j)
        Crow[j] = act ? C_den[s * SUB + j] : 0.f;
    float wsub = act ? W_ns_sub[s] : 0.f;
    float vo = V_o[0];

    // ---- phase 1a: zero-init windows, stage history + taps ----
    for (int r = lane; r < SUB * WLEN; r += 64) PZw[r] = 0.f;
    for (int r = lane; r < NC * WLEN; r += 64)  Zw[r] = 0.f;
    for (int r = lane; r < SUB * THIST; r += 64) {
        int ss = r / THIST, j = r - ss * THIST;
        PKw[ss * TKST + j] = propk[r];
    }
    for (int r = lane; r < NC * THIST; r += 64) {
        int cc = r / THIST, j = r - cc * THIST;
        HKw[cc * TKST + j] = histk[r];
    }
    ybc[lane] = 0.f;
    __syncthreads();
    {
        int tmin = max(0, wb);
        int tmax = t1 - 2;               // A at t uses history up to t-1
        int nv = tmax - tmin + 1;
        if (nv > 0) {
            for (int r = lane; r < SUB * nv; r += 64) {
                int ss = r / nv;
                int ti = r - ss * nv;
                int t = tmin + ti;
                PZw[ss * WLEN + (t - wb)] = PZ_T[(size_t)ss * T + t];
            }
            for (int r = lane; r < NC * nv; r += 64) {
                int cc = r / nv;
                int ti = r - cc * nv;
                int t = tmin + ti;
                Zw[cc * WLEN + (t - wb)] = Z_T[(size_t)cc * T + t];
            }
        }
    }
    __syncthreads();

    // ---- phase 1b: compute A[s][tl]; consecutive lanes -> different rows ----
    {
        int len4 = len >> 2;
        int nwork = SUB * len4;
        for (int o4 = lane; o4 < nwork; o4 += 64) {
            int ss  = o4 % SUB;          // lane-adjacent = row-adjacent (bank-safe)
            int tl4 = o4 / SUB;
            int tl = 4 * tl4;
            int t = tw + tl;
            float4 sy = *(const float4*)(syn_nsT + (size_t)ss * T + t);
            float th = Theta_ns[ss];
            float u0 = sy.x + th, u1 = sy.y + th, u2 = sy.z + th, u3 = sy.w + th;
            {
                const float* bp = &PZw[ss * WLEN];
                const float* pk = &PKw[ss * TKST];
                float pa = bp[tl + 52], pb = bp[tl + 51], pc = bp[tl + 50], pd = bp[tl + 49];
                for (int j = 0; j < THIST; ++j) {
                    float k = pk[j];
                    u3 = fmaf(pa, k, u3); u2 = fmaf(pb, k, u2);
                    u1 = fmaf(pc, k, u1); u0 = fmaf(pd, k, u0);
                    pa = pb; pb = pc; pc = pd;
                    pd = bp[max(0, tl + 48 - j)];   // j=THIST-1 prefetch unused
                }
            }
            if (ss >= 1) {
                const float* bz = &Zw[(ss - 1) * WLEN];
                const float* hk = &HKw[(ss - 1) * TKST];
                float pa = bz[tl + 52], pb = bz[tl + 51], pc = bz[tl + 50], pd = bz[tl + 49];
                for (int j = 0; j < THIST; ++j) {
                    float k = hk[j];
                    u3 = fmaf(pa, k, u3); u2 = fmaf(pb, k, u2);
                    u1 = fmaf(pc, k, u1); u0 = fmaf(pd, k, u0);
                    pa = pb; pb = pc; pc = pd;
                    pd = bz[max(0, tl + 48 - j)];
                }
            }
            *(float4*)(&S[ss * ACHP + tl]) = make_float4(u0, u1, u2, u3);
        }
    }
    __syncthreads();

    // ---- phase 2: serial Y recurrence over len steps ----
    float4 cur = act ? *(float4*)(&S[s * ACHP]) : make_float4(0.f, 0.f, 0.f, 0.f);
    for (int g = 0; g < len; g += 4) {
        float4 nxt = (act && g + 4 < len) ? *(float4*)(&S[s * ACHP + g + 4]) : cur;
        #pragma unroll
        for (int q = 0; q < 4; ++q) {
            float a = (q == 0) ? cur.x : (q == 1) ? cur.y : (q == 2) ? cur.z : cur.w;
            __builtin_amdgcn_wave_barrier();
            float4 Y0 = *(const float4*)(&ybc[0]);
            float4 Y1 = *(const float4*)(&ybc[4]);
            float4 Y2 = *(const float4*)(&ybc[8]);
            float4 Y3 = *(const float4*)(&ybc[12]);
            float4 Y4 = *(const float4*)(&ybc[16]);
            float u0 = a, u1 = 0.f, u2 = 0.f, u3 = 0.f;
            u0 += Crow[0]  * Y0.x;  u1 += Crow[1]  * Y0.y;
            u2 += Crow[2]  * Y0.z;  u3 += Crow[3]  * Y0.w;
            u0 += Crow[4]  * Y1.x;  u1 += Crow[5]  * Y1.y;
            u2 += Crow[6]  * Y1.z;  u3 += Crow[7]  * Y1.w;
            u0 += Crow[8]  * Y2.x;  u1 += Crow[9]  * Y2.y;
            u2 += Crow[10] * Y2.z;  u3 += Crow[11] * Y2.w;
            u0 += Crow[12] * Y3.x;  u1 += Crow[13] * Y3.y;
            u2 += Crow[14] * Y3.z;  u3 += Crow[15] * Y3.w;
            u0 += Crow[16] * Y4.x;  u1 += Crow[17] * Y4.y;
            u2 += Crow[18] * Y4.z;  u3 += Crow[19] * Y4.w;
            float u = (u0 + u1) + (u2 + u3);
            float y = wsub / (1.f + __expf(-u));   // lanes>=20 -> 0
            __builtin_amdgcn_wave_barrier();
            ybc[lane] = y;
            int tl = g + q;
            if (act) SY[tl * SUB + s] = y;
        }
        cur = nxt;
    }
    __syncthreads();
    // ---- bulk coalesced store of live part ----
    for (int r = lane; r < len * SUB; r += 64) {
        int tl = r / SUB;
        int cc = r - tl * SUB;
        int tg = tw + tl;
        if (tg >= t0) {
            float y = SY[r];
            if (cc == 0) Vout[tg] = y + vo;
            else         Yout[(size_t)tg * NC + (cc - 1)] = y;
        }
    }
}

// ---------------------------------------------------------------------------
extern "C" void kernel_launch(void* const* d_in, const int* in_sizes, int n_in,
                              void* d_out, int out_size, void* d_ws, size_t ws_size,
                              hipStream_t stream)
{
    const float* S_e          = (const float*)d_in[0];
    const float* S_i          = (const float*)d_in[1];
    const float* C_den        = (const float*)d_in[2];
    const float* C_syn_e      = (const float*)d_in[3];
    const float* C_syn_i      = (const float*)d_in[4];
    const float* W_s_syn      = (const float*)d_in[5];
    const float* W_ns_syn     = (const float*)d_in[6];
    const float* Delta_ns_syn = (const float*)d_in[7];
    const float* W_ns_sub     = (const float*)d_in[8];
    const float* V_o          = (const float*)d_in[9];
    const float* Theta_s      = (const float*)d_in[10];
    const float* Theta_ns     = (const float*)d_in[11];
    const float* W_ns_hist    = (const float*)d_in[12];
    const float* W_s_prop     = (const float*)d_in[13];
    const float* W_ns_prop    = (const float*)d_in[14];
    const float* spike_decay  = (const float*)d_in[15];

    int E = in_sizes[3] / SUB;
    int I = in_sizes[4] / SUB;
    int T = in_sizes[0] / E;

    float* out  = (float*)d_out;
    float* Vout = out;                           // [T]
    float* Yout = out + (size_t)T;               // [T, 19]
    float* Zout = out + (size_t)T * (1 + NC);    // [T, 19]
    float* Xout = out + (size_t)T * (1 + 2*NC);  // [T, 19]

    float* w       = (float*)d_ws;
    float* in_eT   = w;  w += (size_t)SUB * T;
    float* in_iT   = w;  w += (size_t)SUB * T;
    float* syn_sT  = w;  w += (size_t)NC * T;
    float* syn_nsT = w;  w += (size_t)SUB * T;
    float* PZ_T    = w;  w += (size_t)SUB * T;
    float* Z_T     = w;  w += (size_t)SUB * T;
    float* ke      = w;  w += SUB * TSYN;
    float* ki      = w;  w += SUB * TSYN;
    float* histk   = w;  w += NC * THIST;
    float* propk   = w;  w += SUB * THIST;
    int*   ae      = (int*)w;
    int*   ai      = ae + E;

    int NB = (T + LSEG - 1) / LSEG;   // time-parallel blocks (625 at T=10000)
    int T4 = T >> 2;
    int NCONV = (SUB * T4 + 63) / 64; // conv blocks appended to spk dispatch

    int nprep = E + I + SUB * 2 * TSYN + NC * THIST + SUB * THIST;
    hipLaunchKernelGGL(k_prep, dim3((nprep + 255) / 256), dim3(256), 0, stream,
                       C_syn_e, C_syn_i, W_ns_syn, Delta_ns_syn, W_ns_hist, W_ns_prop,
                       ae, ai, ke, ki, histk, propk, E, I);
    hipLaunchKernelGGL(k_insum, dim3((T + 3) / 4), dim3(256), 0, stream,
                       S_e, S_i, ae, ai, W_s_syn, in_eT, in_iT, syn_sT, T, E, I);
    hipLaunchKernelGGL(k_spkconv, dim3(NB + NCONV), dim3(64), 0, stream,
                       syn_sT, Theta_s, spike_decay, C_den, W_s_prop,
                       Zout, Xout, Z_T, PZ_T,
                       in_eT, in_iT, ke, ki, syn_nsT, T, NB);
    hipLaunchKernelGGL(k_yA, dim3(NB), dim3(64), 0, stream,
                       syn_nsT, PZ_T, Z_T, histk, propk, Theta_ns,
                       C_den, W_ns_sub, V_o, Vout, Yout, T);
}

// Round 14
// 255.014 us; speedup vs baseline: 1.0553x; 1.0553x over previous
//
#include <hip/hip_runtime.h>
#include <math.h>

#define SUB 20       // sub_no
#define NC 19        // sub_no - 1
#define TSYN 200
#define THIST 50
#define BNUM 3
#define LSEG 16      // live segment length per block (NB=625 at T=10000)
#define WARMS 32     // spike warm-up steps: decay<=0.4 by construction -> 0.4^32~2e-13
#define WARMY 36     // Y warm-up: empirical rho<=0.85 (R7/R8 A/B) -> 0.85^36~3e-3 << 2e-2
#define SCH 64       // spk staging chunk (>= LSEG+WARMS = 48)
#define SCHP (SCH+4)
#define YLEN (LSEG+WARMY)   // 52: per-block step window in k_yA
#define ACHP (YLEN+4)       // 56: A-buffer row stride
#define WLEN (THIST+YLEN+5) // 107: odd row stride (11 mod 32) -> conflict-free banks
#define TKST 51             // padded tap-row stride (19 mod 32, odd) -> conflict-free

// ---------------------------------------------------------------------------
// k_prep: assignment indices from one-hot C_syn, plus the three alpha-basis
// kernels (syn with delta shift, hist, prop).
// ---------------------------------------------------------------------------
__global__ void k_prep(const float* __restrict__ C_syn_e, const float* __restrict__ C_syn_i,
                       const float* __restrict__ W_ns_syn, const float* __restrict__ Delta_ns_syn,
                       const float* __restrict__ W_ns_hist, const float* __restrict__ W_ns_prop,
                       int* __restrict__ ae, int* __restrict__ ai,
                       float* __restrict__ ke, float* __restrict__ ki,
                       float* __restrict__ histk, float* __restrict__ propk,
                       int E, int I)
{
    int idx = blockIdx.x * blockDim.x + threadIdx.x;
    if (idx < E) {
        int a = 0;
        for (int s = 0; s < SUB; ++s) if (C_syn_e[(size_t)s * E + idx] != 0.f) a = s;
        ae[idx] = a;
        return;
    }
    idx -= E;
    if (idx < I) {
        int a = 0;
        for (int s = 0; s < SUB; ++s) if (C_syn_i[(size_t)s * I + idx] != 0.f) a = s;
        ai[idx] = a;
        return;
    }
    idx -= I;
    if (idx < SUB * 2 * TSYN) {
        int j   = idx % TSYN;
        int rem = idx / TSYN;
        int c2  = rem & 1;
        int s   = rem >> 1;
        float delta = expf(Delta_ns_syn[s * 2 + c2]);
        float ts = fmaxf((float)j - delta, 0.f);
        float acc = 0.f;
        for (int b = 0; b < BNUM; ++b) {
            float tau = expf((float)b);
            float tt = ts / tau;
            acc += W_ns_syn[s * 6 + b * 2 + c2] * tt * expf(-tt);
        }
        if (c2 == 0) ke[s * TSYN + j] = acc; else ki[s * TSYN + j] = acc;
        return;
    }
    idx -= SUB * 2 * TSYN;
    if (idx < NC * THIST) {
        int j = idx % THIST, c = idx / THIST;
        float acc = 0.f;
        for (int b = 0; b < BNUM; ++b) {
            float tau = expf((float)b);
            float tt = (float)j / tau;
            acc += W_ns_hist[c * 3 + b] * tt * expf(-tt);
        }
        histk[c * THIST + j] = acc;
        return;
    }
    idx -= NC * THIST;
    if (idx < SUB * THIST) {
        int j = idx % THIST, s = idx / THIST;
        float acc = 0.f;
        for (int b = 0; b < BNUM; ++b) {
            float tau = expf((float)b);
            float tt = (float)j / tau;
            acc += W_ns_prop[s * 3 + b] * tt * expf(-tt);
        }
        propk[s * THIST + j] = acc;
    }
}

// ---------------------------------------------------------------------------
// k_insum: segment-sum per timestep (1 timestep/block: max TLP — measured
// faster than 4-t batching, R13 post-mortem). float4 spike loads ->
// transposed [s][t] layouts + fused somatic drive syn_sT[c][t].
// ---------------------------------------------------------------------------
__global__ void k_insum(const float* __restrict__ Se, const float* __restrict__ Si,
                        const int* __restrict__ ae, const int* __restrict__ ai,
                        const float* __restrict__ W_s_syn,
                        float* __restrict__ in_eT, float* __restrict__ in_iT,
                        float* __restrict__ syn_sT,
                        int T, int E, int I)
{
    int t = blockIdx.x;
    __shared__ float le[SUB], li[SUB];
    if (threadIdx.x < SUB) { le[threadIdx.x] = 0.f; li[threadIdx.x] = 0.f; }
    __syncthreads();
    const float* Ser = Se + (size_t)t * E;
    const float* Sir = Si + (size_t)t * I;
    int E4 = E >> 2, I4 = I >> 2;
    for (int e4 = threadIdx.x; e4 < E4; e4 += blockDim.x) {
        float4 v = *(const float4*)(Ser + 4 * e4);
        if (v.x != 0.f) atomicAdd(&le[ae[4 * e4 + 0]], v.x);
        if (v.y != 0.f) atomicAdd(&le[ae[4 * e4 + 1]], v.y);
        if (v.z != 0.f) atomicAdd(&le[ae[4 * e4 + 2]], v.z);
        if (v.w != 0.f) atomicAdd(&le[ae[4 * e4 + 3]], v.w);
    }
    for (int e = 4 * E4 + threadIdx.x; e < E; e += blockDim.x) {
        float v = Ser[e];
        if (v != 0.f) atomicAdd(&le[ae[e]], v);
    }
    for (int i4 = threadIdx.x; i4 < I4; i4 += blockDim.x) {
        float4 v = *(const float4*)(Sir + 4 * i4);
        if (v.x != 0.f) atomicAdd(&li[ai[4 * i4 + 0]], v.x);
        if (v.y != 0.f) atomicAdd(&li[ai[4 * i4 + 1]], v.y);
        if (v.z != 0.f) atomicAdd(&li[ai[4 * i4 + 2]], v.z);
        if (v.w != 0.f) atomicAdd(&li[ai[4 * i4 + 3]], v.w);
    }
    for (int i = 4 * I4 + threadIdx.x; i < I; i += blockDim.x) {
        float v = Sir[i];
        if (v != 0.f) atomicAdd(&li[ai[i]], v);
    }
    __syncthreads();
    int s = threadIdx.x;
    if (s < SUB) {
        in_eT[(size_t)s * T + t] = le[s];
        in_iT[(size_t)s * T + t] = li[s];
        if (s >= 1)
            syn_sT[(size_t)(s - 1) * T + t] =
                le[s] * W_s_syn[s * 2 + 0] + li[s] * W_s_syn[s * 2 + 1];
    }
}

// ---------------------------------------------------------------------------
// k_spkconv: FUSED dispatch. Blocks [0,NB): time-parallel spike recurrence
// (16-step live + 32-step warm-up; per-step math identical to R5-R13;
// epilogue computes Z/X outputs, transposed Z_T and fused PZ_T). Blocks
// [NB,...): 200-tap causal conv hidden under the latency-bound spike blocks.
// ---------------------------------------------------------------------------
__global__ __launch_bounds__(64) void k_spkconv(
                      const float* __restrict__ syn_sT,
                      const float* __restrict__ Theta_s, const float* __restrict__ spike_decay,
                      const float* __restrict__ C_den, const float* __restrict__ W_s_prop,
                      float* __restrict__ Zout, float* __restrict__ Xout,
                      float* __restrict__ Z_T, float* __restrict__ PZ_T,
                      const float* __restrict__ in_eT, const float* __restrict__ in_iT,
                      const float* __restrict__ ke, const float* __restrict__ ki,
                      float* __restrict__ syn_nsT,
                      int T, int NB)
{
    __shared__ float S[NC * SCHP];      // staged syn input ([c][tl], float4 rows)
    __shared__ float SX[SCH * SUB];     // buffered x ([tl][c], stride 20)
    __shared__ unsigned ZM[SCH];        // buffered z ballot masks
    __shared__ float PZb[LSEG * SUB];   // fused-pz scratch ([tl][s])
    int lane = threadIdx.x;

    if (blockIdx.x >= NB) {
        // ---- conv part: 4 outputs/thread, sliding-window registers ----
        int T4 = T >> 2;
        int idx = (blockIdx.x - NB) * 64 + lane;
        if (idx >= SUB * T4) return;
        int s = idx / T4, t4 = idx - s * T4;
        int t = 4 * t4;
        const float* be = in_eT + (size_t)s * T;
        const float* bi = in_iT + (size_t)s * T;
        const float* kes = ke + s * TSYN;
        const float* kis = ki + s * TSYN;
        float ea = be[t + 3], eb = be[t + 2], ec = be[t + 1], ed = be[t];
        float ia = bi[t + 3], ib = bi[t + 2], ic = bi[t + 1], id = bi[t];
        float a0 = 0.f, a1 = 0.f, a2 = 0.f, a3 = 0.f;
        int jend = min(TSYN - 1, t + 3);
        for (int j = 0; j <= jend; ++j) {
            float kej = kes[j], kij = kis[j];
            a3 = fmaf(ea, kej, a3); a3 = fmaf(ia, kij, a3);
            a2 = fmaf(eb, kej, a2); a2 = fmaf(ib, kij, a2);
            a1 = fmaf(ec, kej, a1); a1 = fmaf(ic, kij, a1);
            a0 = fmaf(ed, kej, a0); a0 = fmaf(id, kij, a0);
            ea = eb; eb = ec; ec = ed;
            ia = ib; ib = ic; ic = id;
            int off = t - 1 - j;
            ed = (off >= 0) ? be[off] : 0.f;
            id = (off >= 0) ? bi[off] : 0.f;
        }
        *(float4*)(syn_nsT + (size_t)s * T + t) = make_float4(a0, a1, a2, a3);
        return;
    }

    // ---- spike part ----
    int c = lane;
    bool act = c < NC;
    int t0 = blockIdx.x * LSEG;
    if (t0 >= T) return;
    int t1 = min(t0 + LSEG, T);
    int tw = max(0, t0 - WARMS);

    float M[NC];
    #pragma unroll
    for (int j = 0; j < NC; ++j)
        M[j] = act ? C_den[(c + 1) * SUB + (j + 1)] * W_s_prop[j] : 0.f;
    float Cp[NC];                        // row for fused PZ: C_den[lane][c+1]
    #pragma unroll
    for (int j = 0; j < NC; ++j)
        Cp[j] = (lane < SUB) ? C_den[lane * SUB + (j + 1)] : 0.f;
    float theta = act ? Theta_s[c] : 0.f;
    float decay = act ? spike_decay[c] : 0.f;

    float x = 0.f;
    unsigned zlo = 0u;
    {
        int tc = tw;
        int len = t1 - tw;               // <= 48, multiple of 4
        __syncthreads();
        for (int r = lane; r < (NC * SCH) / 4; r += 64) {
            int e = r * 4;
            int cc = e >> 6;           // e / SCH
            int tl = e & (SCH - 1);    // e % SCH
            if (tl < len) {
                float4 v = *(const float4*)(syn_sT + (size_t)cc * T + tc + tl);
                *(float4*)(&S[cc * SCHP + tl]) = v;
            }
        }
        __syncthreads();
        float4 cur = act ? *(float4*)(&S[c * SCHP]) : make_float4(0.f, 0.f, 0.f, 0.f);
        for (int g = 0; g < len; g += 4) {
            float4 nxt = (act && g + 4 < len) ? *(float4*)(&S[c * SCHP + g + 4]) : cur;
            #pragma unroll
            for (int q = 0; q < 4; ++q) {
                float syn = (q == 0) ? cur.x : (q == 1) ? cur.y : (q == 2) ? cur.z : cur.w;
                float P = 0.f;
                #pragma unroll
                for (int j = 0; j < NC; ++j) {
                    float b = (float)((zlo >> j) & 1u);
                    P = fmaf(b, M[j], P);               // exact: b in {0,1}
                }
                float xin = fmaf(x, decay, syn);
                xin += P;
                xin += theta;
                bool zb = xin >= 0.f;
                zlo = (unsigned)__ballot(zb);
                x = zb ? 0.f : xin;
                int tl = g + q;
                if (act) SX[tl * SUB + c] = x;
                if (lane == NC) ZM[tl] = zlo;
            }
            cur = nxt;
        }
        __syncthreads();
        int tls = t0 - tw;                  // live range start within chunk
        int nl  = len - tls;                // live steps (== t1 - t0)
        // fused k_pz: PZ[s][u] from ballot masks (parallel across lanes)
        if (lane < SUB) {
            for (int tl = 0; tl < nl; ++tl) {
                unsigned m = ZM[tls + tl];
                float acc = 0.f;
                #pragma unroll
                for (int j = 0; j < NC; ++j)
                    acc = fmaf((float)((m >> j) & 1u), Cp[j], acc);
                PZb[tl * SUB + lane] = acc;
            }
        }
        __syncthreads();
        for (int r = lane; r < nl * NC; r += 64) {
            int tl = r / NC;
            int cc = r - tl * NC;
            size_t o = (size_t)(t0 + tl) * NC + cc;
            Zout[o] = (float)((ZM[tls + tl] >> cc) & 1u);
            Xout[o] = SX[(tls + tl) * SUB + cc];
        }
        for (int r = lane; r < nl * NC; r += 64) {
            int cc = r / nl;
            int tl = r - cc * nl;
            Z_T[(size_t)cc * T + (t0 + tl)] = (float)((ZM[tls + tl] >> cc) & 1u);
        }
        for (int r = lane; r < nl * SUB; r += 64) {
            int cc = r / nl;
            int tl = r - cc * nl;
            PZ_T[(size_t)cc * T + (t0 + tl)] = PZb[tl * SUB + cc];
        }
    }
}

// ---------------------------------------------------------------------------
// k_yA: FUSED A-computation + Y recurrence, TIME-PARALLEL (625 blocks x
// 16-step live + 36-step warm-up). Phase 1: stage PZ_T/Z_T history window
// (zero-padded below t=0 -> branchless tap loops; odd row strides 107/51,
// lane-adjacent rows) + compute A[s][tl] into S. Phase 2: serial Y loop,
// per-step math identical to R5-R13.
// ---------------------------------------------------------------------------
__global__ __launch_bounds__(64) void k_yA(
                    const float* __restrict__ syn_nsT,
                    const float* __restrict__ PZ_T, const float* __restrict__ Z_T,
                    const float* __restrict__ histk, const float* __restrict__ propk,
                    const float* __restrict__ Theta_ns,
                    const float* __restrict__ C_den, const float* __restrict__ W_ns_sub,
                    const float* __restrict__ V_o,
                    float* __restrict__ Vout, float* __restrict__ Yout, int T)
{
    __shared__ float S[SUB * ACHP];     // A ([s][tl])
    __shared__ float PZw[SUB * WLEN];   // PZ history window, zero-padded, stride 107
    __shared__ float Zw[NC * WLEN];     // Z history window, zero-padded, stride 107
    __shared__ float PKw[SUB * TKST];   // prop taps, stride 51
    __shared__ float HKw[NC * TKST];    // hist taps, stride 51
    __shared__ float SY[YLEN * SUB];    // buffered y ([tl][s])
    __shared__ __align__(16) float ybc[64];
    int lane = threadIdx.x;
    int s = lane;
    bool act = s < SUB;
    int t0 = blockIdx.x * LSEG;
    if (t0 >= T) return;
    int t1 = min(t0 + LSEG, T);
    int tw = max(0, t0 - WARMY);
    int len = t1 - tw;                   // <= 52, multiple of 4
    int wb = tw - THIST;                 // window base (may be negative)

    float Crow[SUB];
    #pragma unroll
    for (int j = 0; j < SUB; ++j)
        Crow[j] = act ? C_den[s * SUB + j] : 0.f;
    float wsub = act ? W_ns_sub[s] : 0.f;
    float vo = V_o[0];

    // ---- phase 1a: zero-init windows, stage history + taps ----
    for (int r = lane; r < SUB * WLEN; r += 64) PZw[r] = 0.f;
    for (int r = lane; r < NC * WLEN; r += 64)  Zw[r] = 0.f;
    for (int r = lane; r < SUB * THIST; r += 64) {
        int ss = r / THIST, j = r - ss * THIST;
        PKw[ss * TKST + j] = propk[r];
    }
    for (int r = lane; r < NC * THIST; r += 64) {
        int cc = r / THIST, j = r - cc * THIST;
        HKw[cc * TKST + j] = histk[r];
    }
    ybc[lane] = 0.f;
    __syncthreads();
    {
        int tmin = max(0, wb);
        int tmax = t1 - 2;               // A at t uses history up to t-1
        int nv = tmax - tmin + 1;
        if (nv > 0) {
            for (int r = lane; r < SUB * nv; r += 64) {
                int ss = r / nv;
                int ti = r - ss * nv;
                int t = tmin + ti;
                PZw[ss * WLEN + (t - wb)] = PZ_T[(size_t)ss * T + t];
            }
            for (int r = lane; r < NC * nv; r += 64) {
                int cc = r / nv;
                int ti = r - cc * nv;
                int t = tmin + ti;
                Zw[cc * WLEN + (t - wb)] = Z_T[(size_t)cc * T + t];
            }
        }
    }
    __syncthreads();

    // ---- phase 1b: compute A[s][tl]; consecutive lanes -> different rows ----
    {
        int len4 = len >> 2;
        int nwork = SUB * len4;
        for (int o4 = lane; o4 < nwork; o4 += 64) {
            int ss  = o4 % SUB;          // lane-adjacent = row-adjacent (bank-safe)
            int tl4 = o4 / SUB;
            int tl = 4 * tl4;
            int t = tw + tl;
            float4 sy = *(const float4*)(syn_nsT + (size_t)ss * T + t);
            float th = Theta_ns[ss];
            float u0 = sy.x + th, u1 = sy.y + th, u2 = sy.z + th, u3 = sy.w + th;
            {
                const float* bp = &PZw[ss * WLEN];
                const float* pk = &PKw[ss * TKST];
                float pa = bp[tl + 52], pb = bp[tl + 51], pc = bp[tl + 50], pd = bp[tl + 49];
                for (int j = 0; j < THIST; ++j) {
                    float k = pk[j];
                    u3 = fmaf(pa, k, u3); u2 = fmaf(pb, k, u2);
                    u1 = fmaf(pc, k, u1); u0 = fmaf(pd, k, u0);
                    pa = pb; pb = pc; pc = pd;
                    pd = bp[max(0, tl + 48 - j)];   // j=THIST-1 prefetch unused
                }
            }
            if (ss >= 1) {
                const float* bz = &Zw[(ss - 1) * WLEN];
                const float* hk = &HKw[(ss - 1) * TKST];
                float pa = bz[tl + 52], pb = bz[tl + 51], pc = bz[tl + 50], pd = bz[tl + 49];
                for (int j = 0; j < THIST; ++j) {
                    float k = hk[j];
                    u3 = fmaf(pa, k, u3); u2 = fmaf(pb, k, u2);
                    u1 = fmaf(pc, k, u1); u0 = fmaf(pd, k, u0);
                    pa = pb; pb = pc; pc = pd;
                    pd = bz[max(0, tl + 48 - j)];
                }
            }
            *(float4*)(&S[ss * ACHP + tl]) = make_float4(u0, u1, u2, u3);
        }
    }
    __syncthreads();

    // ---- phase 2: serial Y recurrence over len steps ----
    float4 cur = act ? *(float4*)(&S[s * ACHP]) : make_float4(0.f, 0.f, 0.f, 0.f);
    for (int g = 0; g < len; g += 4) {
        float4 nxt = (act && g + 4 < len) ? *(float4*)(&S[s * ACHP + g + 4]) : cur;
        #pragma unroll
        for (int q = 0; q < 4; ++q) {
            float a = (q == 0) ? cur.x : (q == 1) ? cur.y : (q == 2) ? cur.z : cur.w;
            __builtin_amdgcn_wave_barrier();
            float4 Y0 = *(const float4*)(&ybc[0]);
            float4 Y1 = *(const float4*)(&ybc[4]);
            float4 Y2 = *(const float4*)(&ybc[8]);
            float4 Y3 = *(const float4*)(&ybc[12]);
            float4 Y4 = *(const float4*)(&ybc[16]);
            float u0 = a, u1 = 0.f, u2 = 0.f, u3 = 0.f;
            u0 += Crow[0]  * Y0.x;  u1 += Crow[1]  * Y0.y;
            u2 += Crow[2]  * Y0.z;  u3 += Crow[3]  * Y0.w;
            u0 += Crow[4]  * Y1.x;  u1 += Crow[5]  * Y1.y;
            u2 += Crow[6]  * Y1.z;  u3 += Crow[7]  * Y1.w;
            u0 += Crow[8]  * Y2.x;  u1 += Crow[9]  * Y2.y;
            u2 += Crow[10] * Y2.z;  u3 += Crow[11] * Y2.w;
            u0 += Crow[12] * Y3.x;  u1 += Crow[13] * Y3.y;
            u2 += Crow[14] * Y3.z;  u3 += Crow[15] * Y3.w;
            u0 += Crow[16] * Y4.x;  u1 += Crow[17] * Y4.y;
            u2 += Crow[18] * Y4.z;  u3 += Crow[19] * Y4.w;
            float u = (u0 + u1) + (u2 + u3);
            float y = wsub / (1.f + __expf(-u));   // lanes>=20 -> 0
            __builtin_amdgcn_wave_barrier();
            ybc[lane] = y;
            int tl = g + q;
            if (act) SY[tl * SUB + s] = y;
        }
        cur = nxt;
    }
    __syncthreads();
    // ---- bulk coalesced store of live part ----
    for (int r = lane; r < len * SUB; r += 64) {
        int tl = r / SUB;
        int cc = r - tl * SUB;
        int tg = tw + tl;
        if (tg >= t0) {
            float y = SY[r];
            if (cc == 0) Vout[tg] = y + vo;
            else         Yout[(size_t)tg * NC + (cc - 1)] = y;
        }
    }
}

// ---------------------------------------------------------------------------
extern "C" void kernel_launch(void* const* d_in, const int* in_sizes, int n_in,
                              void* d_out, int out_size, void* d_ws, size_t ws_size,
                              hipStream_t stream)
{
    const float* S_e          = (const float*)d_in[0];
    const float* S_i          = (const float*)d_in[1];
    const float* C_den        = (const float*)d_in[2];
    const float* C_syn_e      = (const float*)d_in[3];
    const float* C_syn_i      = (const float*)d_in[4];
    const float* W_s_syn      = (const float*)d_in[5];
    const float* W_ns_syn     = (const float*)d_in[6];
    const float* Delta_ns_syn = (const float*)d_in[7];
    const float* W_ns_sub     = (const float*)d_in[8];
    const float* V_o          = (const float*)d_in[9];
    const float* Theta_s      = (const float*)d_in[10];
    const float* Theta_ns     = (const float*)d_in[11];
    const float* W_ns_hist    = (const float*)d_in[12];
    const float* W_s_prop     = (const float*)d_in[13];
    const float* W_ns_prop    = (const float*)d_in[14];
    const float* spike_decay  = (const float*)d_in[15];

    int E = in_sizes[3] / SUB;
    int I = in_sizes[4] / SUB;
    int T = in_sizes[0] / E;

    float* out  = (float*)d_out;
    float* Vout = out;                           // [T]
    float* Yout = out + (size_t)T;               // [T, 19]
    float* Zout = out + (size_t)T * (1 + NC);    // [T, 19]
    float* Xout = out + (size_t)T * (1 + 2*NC);  // [T, 19]

    float* w       = (float*)d_ws;
    float* in_eT   = w;  w += (size_t)SUB * T;
    float* in_iT   = w;  w += (size_t)SUB * T;
    float* syn_sT  = w;  w += (size_t)NC * T;
    float* syn_nsT = w;  w += (size_t)SUB * T;
    float* PZ_T    = w;  w += (size_t)SUB * T;
    float* Z_T     = w;  w += (size_t)SUB * T;
    float* ke      = w;  w += SUB * TSYN;
    float* ki      = w;  w += SUB * TSYN;
    float* histk   = w;  w += NC * THIST;
    float* propk   = w;  w += SUB * THIST;
    int*   ae      = (int*)w;
    int*   ai      = ae + E;

    int NB = (T + LSEG - 1) / LSEG;   // time-parallel blocks (625 at T=10000)
    int T4 = T >> 2;
    int NCONV = (SUB * T4 + 63) / 64; // conv blocks appended to spk dispatch

    int nprep = E + I + SUB * 2 * TSYN + NC * THIST + SUB * THIST;
    hipLaunchKernelGGL(k_prep, dim3((nprep + 255) / 256), dim3(256), 0, stream,
                       C_syn_e, C_syn_i, W_ns_syn, Delta_ns_syn, W_ns_hist, W_ns_prop,
                       ae, ai, ke, ki, histk, propk, E, I);
    hipLaunchKernelGGL(k_insum, dim3(T), dim3(256), 0, stream,
                       S_e, S_i, ae, ai, W_s_syn, in_eT, in_iT, syn_sT, T, E, I);
    hipLaunchKernelGGL(k_spkconv, dim3(NB + NCONV), dim3(64), 0, stream,
                       syn_sT, Theta_s, spike_decay, C_den, W_s_prop,
                       Zout, Xout, Z_T, PZ_T,
                       in_eT, in_iT, ke, ki, syn_nsT, T, NB);
    hipLaunchKernelGGL(k_yA, dim3(NB), dim3(64), 0, stream,
                       syn_nsT, PZ_T, Z_T, histk, propk, Theta_ns,
                       C_den, W_ns_sub, V_o, Vout, Yout, T);
}